// Round 7
// baseline (87.251 us; speedup 1.0000x reference)
//
#include <hip/hip_runtime.h>
#include <math.h>

#define NQ 6
#define DIM 64
#define W1S 65           // padded LDS stride (R2-proven, conflict-free)
#define PI_F 3.14159265358979323846f

typedef int i32x2 __attribute__((ext_vector_type(2)));

// ---------- DPP helpers ----------
template <int CTRL, int ROWM, bool BC>
__device__ __forceinline__ float dpp_add_src(float v) {
  int r = __builtin_amdgcn_update_dpp(0, __float_as_int(v), CTRL, ROWM, 0xF, BC);
  return __int_as_float(r);
}
template <int CTRL>
__device__ __forceinline__ float dpp_mov(float v) {
  int i = __float_as_int(v);
  return __int_as_float(__builtin_amdgcn_update_dpp(i, i, CTRL, 0xF, 0xF, false));
}

// sum over 64 lanes; valid in lane 63 (R2-proven)
__device__ __forceinline__ float red_sum(float v) {
  v += dpp_add_src<0x111, 0xF, true>(v);   // row_shr:1
  v += dpp_add_src<0x112, 0xF, true>(v);   // row_shr:2
  v += dpp_add_src<0x114, 0xF, true>(v);   // row_shr:4
  v += dpp_add_src<0x118, 0xF, true>(v);   // row_shr:8
  v += dpp_add_src<0x142, 0xA, false>(v);  // row_bcast:15 -> rows 1,3
  v += dpp_add_src<0x143, 0xC, false>(v);  // row_bcast:31 -> rows 2,3
  return v;
}
__device__ __forceinline__ float bcast63(float v) {
  return __int_as_float(__builtin_amdgcn_readlane(__float_as_int(v), 63));
}
__device__ __forceinline__ float rdlane(float v, int l) {
  return __int_as_float(__builtin_amdgcn_readlane(__float_as_int(v), l));
}

// ---------- xor-partner exchange, all VALU pipe (validated R4/R6) ----------
template <int W>
__device__ __forceinline__ float shuf(float v, int lane) {
  if constexpr (W == 5) {        // xor 1: quad_perm [1,0,3,2]
    return dpp_mov<0xB1>(v);
  } else if constexpr (W == 4) { // xor 2: quad_perm [2,3,0,1]
    return dpp_mov<0x4E>(v);
  } else if constexpr (W == 3) { // xor 4: select(ror4, ror12)   (R6-validated)
    const float r4  = dpp_mov<0x124>(v);
    const float r12 = dpp_mov<0x12C>(v);
    return (lane & 4) ? r4 : r12;
  } else if constexpr (W == 2) { // xor 8 == row_ror:8           (R4-validated)
    return dpp_mov<0x128>(v);
  } else if constexpr (W == 1) { // xor 16: permlane16_swap      (R4-validated)
#if __has_builtin(__builtin_amdgcn_permlane16_swap)
    i32x2 r = __builtin_amdgcn_permlane16_swap(__float_as_int(v),
                                               __float_as_int(v), false, false);
    return __int_as_float((lane & 16) ? r[0] : r[1]);
#else
    return __int_as_float(__builtin_amdgcn_ds_swizzle(__float_as_int(v), 0x401F));
#endif
  } else {                       // xor 32: permlane32_swap      (R3-validated)
#if __has_builtin(__builtin_amdgcn_permlane32_swap)
    i32x2 r = __builtin_amdgcn_permlane32_swap(__float_as_int(v),
                                               __float_as_int(v), false, false);
    return __int_as_float((lane & 32) ? r[0] : r[1]);
#else
    return __shfl_xor(v, 32, 64);
#endif
  }
}

// ---------- one Rot gate on wire W; c = (ar,ai,br,bi) in registers ----------
template <int W>
__device__ __forceinline__ void gate1(float& re, float& im, float4 c,
                                      float sg, int lane) {
  const float ais = c.y * sg;
  const float brs = c.z * sg;
  const float pr = shuf<W>(re, lane);
  const float pi = shuf<W>(im, lane);
  float nr = c.x * re;
  nr = fmaf(-ais, im, nr);
  nr = fmaf(brs, pr, nr);
  nr = fmaf(-c.w, pi, nr);
  float ni = c.x * im;
  ni = fmaf(ais, re, ni);
  ni = fmaf(brs, pi, ni);
  ni = fmaf(c.w, pr, ni);
  re = nr; im = ni;
}

// composed source index for the CNOT ring of range r
__device__ __forceinline__ int cnot_src(int j, int r) {
  int i = j;
  #pragma unroll
  for (int w = 5; w >= 0; --w) {
    const int cm = 32 >> w;
    const int tm = 32 >> ((w + r) % NQ);
    if (i & cm) i ^= tm;
  }
  return i;
}

__global__ __launch_bounds__(256) void qmaml_v7(
    const float* __restrict__ x,
    const float* __restrict__ W1,
    const float* __restrict__ b1,
    const float* __restrict__ ln_g,
    const float* __restrict__ ln_b,
    const float* __restrict__ W2,
    const float* __restrict__ b2,
    const float* __restrict__ th_sh,
    const float* __restrict__ th_tk,
    const float* __restrict__ Wc,
    const float* __restrict__ bc,
    float* __restrict__ out,
    int B)
{
  __shared__ float w1t[64 * W1S];   // W1^T padded (R2-proven)
  __shared__ float4 coef[18];

  const int tid = threadIdx.x;

  #pragma unroll
  for (int it = 0; it < 16; ++it) {
    const int idx = tid + it * 256;
    w1t[(idx & 63) * W1S + (idx >> 6)] = W1[idx];
  }
  if (tid < 18) {
    const int layer = tid / 6, w = tid % 6;
    const float* th = (layer < 2) ? (th_sh + (layer * 6 + w) * 3)
                                  : (th_tk + w * 3);
    const float phi = th[0], the = th[1], om = th[2];
    float S, C;   sincosf(0.5f * the,        &S,  &C);
    float sS, cS; sincosf(0.5f * (om + phi), &sS, &cS);
    float sD, cD; sincosf(0.5f * (om - phi), &sD, &cD);
    coef[tid] = make_float4(C * cS, -C * sS, -S * cD, S * sD);
  }
  __syncthreads();

  const int lane = tid & 63;
  const int wid = __builtin_amdgcn_readfirstlane(blockIdx.x * 4 + (tid >> 6));
  const int nw = gridDim.x * 4;

  // ---- batch-independent per-lane preloads (R2-identical) ----
  const float b1v = b1[lane];
  const float lgv = ln_g[lane];
  const float lbv = ln_b[lane];
  float w2v[NQ];
  #pragma unroll
  for (int m = 0; m < NQ; ++m) w2v[m] = W2[m * DIM + lane];
  const float b2v = (lane < NQ) ? b2[lane] : 0.0f;
  const float bcv = (lane < 5) ? bc[lane] : 0.0f;
  float sgn[NQ];
  #pragma unroll
  for (int w = 0; w < NQ; ++w) sgn[w] = (lane & (32 >> w)) ? -1.0f : 1.0f;
  float g5[5];
  #pragma unroll
  for (int j = 0; j < 5; ++j) {
    float a = 0.0f;
    #pragma unroll
    for (int w = 0; w < NQ; ++w) {
      const float wc = Wc[j * NQ + w];
      a += (lane & (32 >> w)) ? -wc : wc;
    }
    g5[j] = a;
  }
  const int pa1 = cnot_src(lane, 1) << 2;
  const int pa2 = cnot_src(lane, 2) << 2;

  for (int t = wid; t < B; t += nw) {
    // x row wave-uniform -> scalar (SMEM) loads
    const float* __restrict__ xr =
        x + (size_t)__builtin_amdgcn_readfirstlane(t) * DIM;

    // ---- Linear1 + ReLU: lane j computes h_j ----
    float acc = b1v;
    #pragma unroll
    for (int k = 0; k < DIM; ++k)
      acc = fmaf(w1t[k * W1S + lane], xr[k], acc);
    float h = fmaxf(acc, 0.0f);

    // ---- LayerNorm across lanes ----
    const float mu = bcast63(red_sum(h)) * (1.0f / DIM);
    const float d = h - mu;
    const float var = bcast63(red_sum(d * d)) * (1.0f / DIM);
    const float rs = __builtin_amdgcn_rsqf(var + 1e-5f);
    h = fmaf(d * rs, lgv, lbv);

    // ---- Linear2: angle accumulators land in lanes 0..5 ----
    float y = 0.0f;
    #pragma unroll
    for (int m = 0; m < NQ; ++m) {
      const float r = bcast63(red_sum(w2v[m] * h));
      y = (lane == m) ? r : y;
    }
    y += b2v;

    // ---- prefetch layer-0 coefs; latency covered by trig + state init ----
    float4 k0 = coef[0], k1 = coef[1], k2 = coef[2],
           k3 = coef[3], k4 = coef[4], k5 = coef[5];

    // ---- tanh + half-angle sincos (lane-parallel, once) ----
    const float e = __expf(2.0f * y);
    const float tz = fmaf(-2.0f, __builtin_amdgcn_rcpf(e + 1.0f), 1.0f);
    const float ha = (0.5f * PI_F) * tz;
    const float sv = __sinf(ha);
    const float cv = __cosf(ha);

    // ---- init product state: lane = basis index ----
    float re = (lane & 32) ? rdlane(sv, 0) : rdlane(cv, 0);
    re *= (lane & 16) ? rdlane(sv, 1) : rdlane(cv, 1);
    re *= (lane &  8) ? rdlane(sv, 2) : rdlane(cv, 2);
    re *= (lane &  4) ? rdlane(sv, 3) : rdlane(cv, 3);
    re *= (lane &  2) ? rdlane(sv, 4) : rdlane(cv, 4);
    re *= (lane &  1) ? rdlane(sv, 5) : rdlane(cv, 5);
    float im = 0.0f;

    // ---- layer 0 (ring r=1); stage layer-1 coefs behind each gate ----
    gate1<0>(re, im, k0, sgn[0], lane);  k0 = coef[6];
    gate1<1>(re, im, k1, sgn[1], lane);  k1 = coef[7];
    gate1<2>(re, im, k2, sgn[2], lane);  k2 = coef[8];
    gate1<3>(re, im, k3, sgn[3], lane);  k3 = coef[9];
    gate1<4>(re, im, k4, sgn[4], lane);  k4 = coef[10];
    gate1<5>(re, im, k5, sgn[5], lane);  k5 = coef[11];
    re = __int_as_float(__builtin_amdgcn_ds_bpermute(pa1, __float_as_int(re)));
    im = __int_as_float(__builtin_amdgcn_ds_bpermute(pa1, __float_as_int(im)));

    // ---- layer 1 (ring r=2); stage layer-2 coefs ----
    gate1<0>(re, im, k0, sgn[0], lane);  k0 = coef[12];
    gate1<1>(re, im, k1, sgn[1], lane);  k1 = coef[13];
    gate1<2>(re, im, k2, sgn[2], lane);  k2 = coef[14];
    gate1<3>(re, im, k3, sgn[3], lane);  k3 = coef[15];
    gate1<4>(re, im, k4, sgn[4], lane);  k4 = coef[16];
    gate1<5>(re, im, k5, sgn[5], lane);  k5 = coef[17];
    re = __int_as_float(__builtin_amdgcn_ds_bpermute(pa2, __float_as_int(re)));
    im = __int_as_float(__builtin_amdgcn_ds_bpermute(pa2, __float_as_int(im)));

    // ---- layer 2 (ring r=1) ----
    gate1<0>(re, im, k0, sgn[0], lane);
    gate1<1>(re, im, k1, sgn[1], lane);
    gate1<2>(re, im, k2, sgn[2], lane);
    gate1<3>(re, im, k3, sgn[3], lane);
    gate1<4>(re, im, k4, sgn[4], lane);
    gate1<5>(re, im, k5, sgn[5], lane);
    re = __int_as_float(__builtin_amdgcn_ds_bpermute(pa1, __float_as_int(re)));
    im = __int_as_float(__builtin_amdgcn_ds_bpermute(pa1, __float_as_int(im)));

    // ---- measurement + classifier head ----
    const float p = fmaf(re, re, im * im);
    float o0 = bcast63(red_sum(p * g5[0]));
    float o1 = bcast63(red_sum(p * g5[1]));
    float o2 = bcast63(red_sum(p * g5[2]));
    float o3 = bcast63(red_sum(p * g5[3]));
    float o4 = bcast63(red_sum(p * g5[4]));
    float vout = (lane == 0) ? o0 :
                 (lane == 1) ? o1 :
                 (lane == 2) ? o2 :
                 (lane == 3) ? o3 : o4;
    if (lane < 5) out[(size_t)t * 5 + lane] = vout + bcv;
  }
}

extern "C" void kernel_launch(void* const* d_in, const int* in_sizes, int n_in,
                              void* d_out, int out_size, void* d_ws, size_t ws_size,
                              hipStream_t stream) {
  const float* x     = (const float*)d_in[0];
  const float* W1    = (const float*)d_in[1];
  const float* b1    = (const float*)d_in[2];
  const float* ln_g  = (const float*)d_in[3];
  const float* ln_b  = (const float*)d_in[4];
  const float* W2    = (const float*)d_in[5];
  const float* b2    = (const float*)d_in[6];
  const float* th_sh = (const float*)d_in[7];
  const float* th_tk = (const float*)d_in[8];
  const float* Wc    = (const float*)d_in[9];
  const float* bc    = (const float*)d_in[10];
  float* out = (float*)d_out;

  const int B = in_sizes[0] / DIM;
  int blocks = (B + 3) / 4;
  if (blocks > 2048) blocks = 2048;
  qmaml_v7<<<blocks, 256, 0, stream>>>(x, W1, b1, ln_g, ln_b, W2, b2,
                                       th_sh, th_tk, Wc, bc, out, B);
}

// Round 9
// 66.529 us; speedup vs baseline: 1.3115x; 1.3115x over previous
//
#include <hip/hip_runtime.h>
#include <math.h>

#define NQ 6
#define DIM 64
#define W1S 65           // padded LDS stride (R2-proven)
#define PI_F 3.14159265358979323846f

// ---------- DPP helpers (R2 verbatim) ----------
template <int CTRL, int ROWM, bool BC>
__device__ __forceinline__ float dpp_add_src(float v) {
  int r = __builtin_amdgcn_update_dpp(0, __float_as_int(v), CTRL, ROWM, 0xF, BC);
  return __int_as_float(r);
}

// sum over 64 lanes; valid in lane 63 (R2-proven)
__device__ __forceinline__ float red_sum(float v) {
  v += dpp_add_src<0x111, 0xF, true>(v);   // row_shr:1
  v += dpp_add_src<0x112, 0xF, true>(v);   // row_shr:2
  v += dpp_add_src<0x114, 0xF, true>(v);   // row_shr:4
  v += dpp_add_src<0x118, 0xF, true>(v);   // row_shr:8
  v += dpp_add_src<0x142, 0xA, false>(v);  // row_bcast:15 -> rows 1,3
  v += dpp_add_src<0x143, 0xC, false>(v);  // row_bcast:31 -> rows 2,3
  return v;
}
__device__ __forceinline__ float bcast63(float v) {
  return __int_as_float(__builtin_amdgcn_readlane(__float_as_int(v), 63));
}
__device__ __forceinline__ float rdlane(float v, int l) {
  return __int_as_float(__builtin_amdgcn_readlane(__float_as_int(v), l));
}

// ---------- xor-partner shuffle (R2 verbatim: LDS pipe for 4/8/16/32) ----------
template <int W>
__device__ __forceinline__ float sh_partner(float v) {
  if constexpr (W == 5) {        // xor 1: quad_perm [1,0,3,2]
    int i = __float_as_int(v);
    return __int_as_float(__builtin_amdgcn_update_dpp(i, i, 0xB1, 0xF, 0xF, false));
  } else if constexpr (W == 4) { // xor 2: quad_perm [2,3,0,1]
    int i = __float_as_int(v);
    return __int_as_float(__builtin_amdgcn_update_dpp(i, i, 0x4E, 0xF, 0xF, false));
  } else if constexpr (W == 3) { // xor 4
    return __int_as_float(__builtin_amdgcn_ds_swizzle(__float_as_int(v), 0x101F));
  } else if constexpr (W == 2) { // xor 8
    return __int_as_float(__builtin_amdgcn_ds_swizzle(__float_as_int(v), 0x201F));
  } else if constexpr (W == 1) { // xor 16
    return __int_as_float(__builtin_amdgcn_ds_swizzle(__float_as_int(v), 0x401F));
  } else {                       // xor 32
    return __shfl_xor(v, 32, 64);
  }
}

// ---------- one Rot gate on wire W (R2 verbatim) ----------
template <int W>
__device__ __forceinline__ void gate_w(float& re, float& im, float4 c, int lane) {
  float pr = sh_partner<W>(re);
  float pi = sh_partner<W>(im);
  const bool hi = (lane & (32 >> W)) != 0;
  float sa = hi ? -c.y : c.y;
  float sb = hi ? -c.z : c.z;
  float nr = c.x * re;
  nr = fmaf(-sa, im, nr);
  nr = fmaf(sb, pr, nr);
  nr = fmaf(-c.w, pi, nr);
  float ni = c.x * im;
  ni = fmaf(sa, re, ni);
  ni = fmaf(sb, pi, ni);
  ni = fmaf(c.w, pr, ni);
  re = nr; im = ni;
}

// composed source index for the CNOT ring of range r
__device__ __forceinline__ int cnot_src(int j, int r) {
  int i = j;
  #pragma unroll
  for (int w = 5; w >= 0; --w) {
    const int cm = 32 >> w;
    const int tm = 32 >> ((w + r) % NQ);
    if (i & cm) i ^= tm;
  }
  return i;
}

__global__ __launch_bounds__(256) void qmaml_v9(
    const float* __restrict__ x,
    const float* __restrict__ W1,
    const float* __restrict__ b1,
    const float* __restrict__ ln_g,
    const float* __restrict__ ln_b,
    const float* __restrict__ W2,
    const float* __restrict__ b2,
    const float* __restrict__ th_sh,
    const float* __restrict__ th_tk,
    const float* __restrict__ Wc,
    const float* __restrict__ bc,
    float* __restrict__ out,
    int B)
{
  __shared__ float w1t[64 * W1S];   // W1^T padded: w1t[k*65 + j] = W1[j][k]
  __shared__ float4 coef[18];

  const int tid = threadIdx.x;

  #pragma unroll
  for (int it = 0; it < 16; ++it) {
    const int idx = tid + it * 256;
    w1t[(idx & 63) * W1S + (idx >> 6)] = W1[idx];
  }
  if (tid < 18) {
    const int layer = tid / 6, w = tid % 6;
    const float* th = (layer < 2) ? (th_sh + (layer * 6 + w) * 3)
                                  : (th_tk + w * 3);
    const float phi = th[0], the = th[1], om = th[2];
    float S, C;   sincosf(0.5f * the,        &S,  &C);
    float sS, cS; sincosf(0.5f * (om + phi), &sS, &cS);
    float sD, cD; sincosf(0.5f * (om - phi), &sD, &cD);
    coef[tid] = make_float4(C * cS, -C * sS, -S * cD, S * sD);
  }
  __syncthreads();

  const int lane = tid & 63;
  const int wid = __builtin_amdgcn_readfirstlane(blockIdx.x * 4 + (tid >> 6));
  const int nw = gridDim.x * 4;

  // ---- batch-independent per-lane preloads (R2 verbatim) ----
  const float b1v = b1[lane];
  const float lgv = ln_g[lane];
  const float lbv = ln_b[lane];
  float w2v[NQ];
  #pragma unroll
  for (int m = 0; m < NQ; ++m) w2v[m] = W2[m * DIM + lane];
  const float b2v = (lane < NQ) ? b2[lane] : 0.0f;
  const float bcv = (lane < 5) ? bc[lane] : 0.0f;
  float g5[5];
  #pragma unroll
  for (int j = 0; j < 5; ++j) {
    float a = 0.0f;
    #pragma unroll
    for (int w = 0; w < NQ; ++w) {
      const float wc = Wc[j * NQ + w];
      a += (lane & (32 >> w)) ? -wc : wc;
    }
    g5[j] = a;
  }
  const int pa1 = cnot_src(lane, 1) << 2;
  const int pa2 = cnot_src(lane, 2) << 2;

  for (int t = wid; t < B; t += nw) {
    const float* __restrict__ xr =
        x + (size_t)__builtin_amdgcn_readfirstlane(t) * DIM;

    // ---- Linear1 + ReLU: 4 independent fma chains (new, pure reassoc) ----
    float a0 = b1v, a1 = 0.0f, a2 = 0.0f, a3 = 0.0f;
    #pragma unroll
    for (int k = 0; k < DIM; k += 4) {
      a0 = fmaf(w1t[(k + 0) * W1S + lane], xr[k + 0], a0);
      a1 = fmaf(w1t[(k + 1) * W1S + lane], xr[k + 1], a1);
      a2 = fmaf(w1t[(k + 2) * W1S + lane], xr[k + 2], a2);
      a3 = fmaf(w1t[(k + 3) * W1S + lane], xr[k + 3], a3);
    }
    float h = fmaxf((a0 + a1) + (a2 + a3), 0.0f);

    // ---- one-pass LayerNorm (R5/R6-validated form) ----
    const float s1 = bcast63(red_sum(h)) * (1.0f / DIM);
    const float s2 = bcast63(red_sum(h * h)) * (1.0f / DIM);
    const float rs = __builtin_amdgcn_rsqf(s2 - s1 * s1 + 1e-5f);
    h = fmaf((h - s1) * rs, lgv, lbv);

    // ---- Linear2 (R2 verbatim) ----
    float y = 0.0f;
    #pragma unroll
    for (int m = 0; m < NQ; ++m) {
      const float r = bcast63(red_sum(w2v[m] * h));
      y = (lane == m) ? r : y;
    }
    y += b2v;

    // ---- prefetch layer-0 coefs (R7-validated) ----
    float4 k0 = coef[0], k1 = coef[1], k2 = coef[2],
           k3 = coef[3], k4 = coef[4], k5 = coef[5];

    // ---- tanh + half-angle sincos (R2 verbatim) ----
    const float e = __expf(2.0f * y);
    const float tz = fmaf(-2.0f, __builtin_amdgcn_rcpf(e + 1.0f), 1.0f);
    const float ha = (0.5f * PI_F) * tz;
    const float sv = __sinf(ha);
    const float cv = __cosf(ha);

    // ---- init product state (R2 verbatim) ----
    float re = (lane & 32) ? rdlane(sv, 0) : rdlane(cv, 0);
    re *= (lane & 16) ? rdlane(sv, 1) : rdlane(cv, 1);
    re *= (lane &  8) ? rdlane(sv, 2) : rdlane(cv, 2);
    re *= (lane &  4) ? rdlane(sv, 3) : rdlane(cv, 3);
    re *= (lane &  2) ? rdlane(sv, 4) : rdlane(cv, 4);
    re *= (lane &  1) ? rdlane(sv, 5) : rdlane(cv, 5);
    float im = 0.0f;

    // ---- layer 0 (ring r=1); stage layer-1 coefs (R7-validated) ----
    gate_w<0>(re, im, k0, lane);  k0 = coef[6];
    gate_w<1>(re, im, k1, lane);  k1 = coef[7];
    gate_w<2>(re, im, k2, lane);  k2 = coef[8];
    gate_w<3>(re, im, k3, lane);  k3 = coef[9];
    gate_w<4>(re, im, k4, lane);  k4 = coef[10];
    gate_w<5>(re, im, k5, lane);  k5 = coef[11];
    re = __int_as_float(__builtin_amdgcn_ds_bpermute(pa1, __float_as_int(re)));
    im = __int_as_float(__builtin_amdgcn_ds_bpermute(pa1, __float_as_int(im)));

    // ---- layer 1 (ring r=2); stage layer-2 coefs ----
    gate_w<0>(re, im, k0, lane);  k0 = coef[12];
    gate_w<1>(re, im, k1, lane);  k1 = coef[13];
    gate_w<2>(re, im, k2, lane);  k2 = coef[14];
    gate_w<3>(re, im, k3, lane);  k3 = coef[15];
    gate_w<4>(re, im, k4, lane);  k4 = coef[16];
    gate_w<5>(re, im, k5, lane);  k5 = coef[17];
    re = __int_as_float(__builtin_amdgcn_ds_bpermute(pa2, __float_as_int(re)));
    im = __int_as_float(__builtin_amdgcn_ds_bpermute(pa2, __float_as_int(im)));

    // ---- layer 2 (ring r=1) ----
    gate_w<0>(re, im, k0, lane);
    gate_w<1>(re, im, k1, lane);
    gate_w<2>(re, im, k2, lane);
    gate_w<3>(re, im, k3, lane);
    gate_w<4>(re, im, k4, lane);
    gate_w<5>(re, im, k5, lane);
    re = __int_as_float(__builtin_amdgcn_ds_bpermute(pa1, __float_as_int(re)));
    im = __int_as_float(__builtin_amdgcn_ds_bpermute(pa1, __float_as_int(im)));

    // ---- measurement + classifier head (R2 verbatim) ----
    const float p = fmaf(re, re, im * im);
    float o0 = bcast63(red_sum(p * g5[0]));
    float o1 = bcast63(red_sum(p * g5[1]));
    float o2 = bcast63(red_sum(p * g5[2]));
    float o3 = bcast63(red_sum(p * g5[3]));
    float o4 = bcast63(red_sum(p * g5[4]));
    float vout = (lane == 0) ? o0 :
                 (lane == 1) ? o1 :
                 (lane == 2) ? o2 :
                 (lane == 3) ? o3 : o4;
    if (lane < 5) out[(size_t)t * 5 + lane] = vout + bcv;
  }
}

extern "C" void kernel_launch(void* const* d_in, const int* in_sizes, int n_in,
                              void* d_out, int out_size, void* d_ws, size_t ws_size,
                              hipStream_t stream) {
  const float* x     = (const float*)d_in[0];
  const float* W1    = (const float*)d_in[1];
  const float* b1    = (const float*)d_in[2];
  const float* ln_g  = (const float*)d_in[3];
  const float* ln_b  = (const float*)d_in[4];
  const float* W2    = (const float*)d_in[5];
  const float* b2    = (const float*)d_in[6];
  const float* th_sh = (const float*)d_in[7];
  const float* th_tk = (const float*)d_in[8];
  const float* Wc    = (const float*)d_in[9];
  const float* bc    = (const float*)d_in[10];
  float* out = (float*)d_out;

  const int B = in_sizes[0] / DIM;
  int blocks = (B + 3) / 4;
  if (blocks > 2048) blocks = 2048;
  qmaml_v9<<<blocks, 256, 0, stream>>>(x, W1, b1, ln_g, ln_b, W2, b2,
                                       th_sh, th_tk, Wc, bc, out, B);
}